// Round 4
// baseline (239.998 us; speedup 1.0000x reference)
//
#include <hip/hip_runtime.h>
#include <math.h>

typedef __bf16 bf16_t;
typedef bf16_t bf16x4 __attribute__((ext_vector_type(4)));
typedef bf16_t bf16x8 __attribute__((ext_vector_type(8)));
typedef float  f32x16 __attribute__((ext_vector_type(16)));

#define HH 1024
#define CC 8
#define DD 64
#define FF 32
#define WW 7
#define HP 1018
#define HPAD 1024
#define NF 128
#define QOUT (NF*HP*DD)
#define QWS ((size_t)NF*HPAD*DD)
#define LSTR 72                          // As row stride (bf16): 144 B -> b128 reads conflict-free

#if __has_builtin(__builtin_amdgcn_exp2f)
#define EXP2(x) __builtin_amdgcn_exp2f(x)
#else
#define EXP2(x) __expf((x) * 0.6931471805599453f)
#endif

// Vt: row stride 64 bf16, XOR-swizzled 8-element chunks:
//   addr(row, col) = row*64 + (((col>>3) ^ (row&7) ^ ((row>>2)&7))<<3) + (col&7)
__device__ __forceinline__ int vaddr(int row, int col) {
    return row*64 + ((((col>>3) ^ (row&7) ^ ((row>>2)&7)))<<3) + (col&7);
}

// ---------------- W transpose: Wt[f][c][d][j] -> Wp[f][c][j][d] ----------------
__global__ __launch_bounds__(256) void wprep_kernel(
    const float* __restrict__ Wt, float* __restrict__ Wp)
{
    const int idx = blockIdx.x * 256 + threadIdx.x;
    if (idx < FF*CC*DD*WW) {
        const int j = idx % WW;
        int t = idx / WW;
        const int d = t % DD; t /= DD;
        const int c = t % CC;
        const int f = t / CC;
        Wp[((f*CC + c)*WW + j)*DD + d] = Wt[idx];
    }
}

// ---------------- projection (grouped conv): all f per block, x staged in LDS ----
__global__ __launch_bounds__(256) void conv_kernel(
    const float* __restrict__ x1, const float* __restrict__ x2,
    const float* __restrict__ Wp, bf16_t* __restrict__ q1, bf16_t* __restrict__ q2)
{
    __shared__ float xs[38*512];
    const float* x = blockIdx.z ? x2 : x1;
    bf16_t* q = blockIdx.z ? q2 : q1;
    const int n = blockIdx.y;
    const int hb = blockIdx.x * 32;
    const int tid = threadIdx.x;

    const float4* xg = (const float4*)(x + (size_t)n*HH*512);
    for (int i = tid; i < 38*128; i += 256) {
        const int row = hb + (i >> 7);
        float4 v = {0.f, 0.f, 0.f, 0.f};
        if (row < HH) v = xg[(size_t)row*128 + (i & 127)];
        *(float4*)&xs[(size_t)i*4] = v;
    }
    __syncthreads();

    const int d = tid & 63;
    const int fq = tid >> 6;
    for (int fi = 0; fi < 8; ++fi) {
        const int f = fq*8 + fi;
        float w[CC][WW];
#pragma unroll
        for (int c = 0; c < CC; ++c)
#pragma unroll
            for (int j = 0; j < WW; ++j)
                w[c][j] = Wp[((f*CC + c)*WW + j)*DD + d];
#pragma unroll
        for (int hc = 0; hc < 2; ++hc) {
            float acc[16];
#pragma unroll
            for (int i = 0; i < 16; ++i) acc[i] = 0.f;
#pragma unroll
            for (int rr = 0; rr < 22; ++rr) {
                float xv[CC];
#pragma unroll
                for (int c = 0; c < CC; ++c)
                    xv[c] = xs[(hc*16 + rr)*512 + c*64 + d];
#pragma unroll
                for (int j = 0; j < WW; ++j) {
                    const int i = rr - j;
                    if (i >= 0 && i < 16) {
#pragma unroll
                        for (int c = 0; c < CC; ++c)
                            acc[i] = fmaf(xv[c], w[c][j], acc[i]);
                    }
                }
            }
#pragma unroll
            for (int i = 0; i < 16; ++i) {
                const int h = hb + hc*16 + i;
                const float v = (h < HP) ? acc[i] : 0.f;
                q[((size_t)(n*FF + f)*HPAD + h)*DD + d] = (bf16_t)v;
            }
        }
    }
}

__device__ __forceinline__ float fast_tanh(float x) {
    const float t = __expf(2.f * x);
    return (t - 1.f) / (t + 1.f);
}

// ---------------- fused flash pass (MFMA), 32 h-rows per wave ----------------
// Sᵀ = Q2·Q1ᵀ : C/D col=lane&31 -> h on lanes; row=(reg&3)+8*(reg>>2)+4*(lane>>5) -> g.
// Vt columns in permuted order p(g) matching C-reg k-order; XOR-swizzled banks.
template<int MODE>
__global__ __launch_bounds__(256, 4) void flash(
    const bf16_t* __restrict__ q1, const bf16_t* __restrict__ q2,
    const bf16_t* __restrict__ vsrc, bf16_t* __restrict__ p1out,
    float* __restrict__ out)
{
    __shared__ __align__(16) bf16_t As[64*LSTR];   // q2 tile [g][d], stride 72
    __shared__ __align__(16) bf16_t Vt[64*64];     // V^T tile [d][p(g)], swizzled

    const int head = blockIdx.y;
    const int n = head >> 5, f = head & 31;
    const int tid = threadIdx.x;
    const int w = tid >> 6;
    const int lane = tid & 63;
    const int lid = lane & 31;
    const int half = lane >> 5;
    const int hb = blockIdx.x * 128 + w * 32;      // 32 rows per wave

    const size_t qoff = (size_t)head * HPAD * DD;
    const float SC = 1.442695041f / 1018.f;        // log2(e)/1018
    const int vswz = (lid & 7) ^ (lid >> 2);       // read-side swizzle (dt-independent)

    // staging map: thread loads rows g=4gq..4gq+3, cols 4dq..4dq+3
    const int gq = tid >> 4;
    const int dq = tid & 15;
    const int cgb = 4*((gq>>1)&1) + 8*(gq&1) + 16*(gq>>2);   // permuted col base

    // Q1 B-fragments, persistent in registers (one 32-row block)
    bf16x8 bq1[4];
#pragma unroll
    for (int kt = 0; kt < 4; ++kt)
        bq1[kt] = *(const bf16x8*)&q1[qoff + (size_t)(hb + lid)*DD + 16*kt + 8*half];

    f32x16 O[2] = {};        // [dt]
    float lacc = 0.f;

    // register preload of tile 0
    bf16x4 rA[4], rV[4];
#pragma unroll
    for (int i = 0; i < 4; ++i) {
        rA[i] = *(const bf16x4*)&q2[qoff + (size_t)(4*gq + i)*DD + 4*dq];
        if (MODE == 1)
            rV[i] = *(const bf16x4*)&vsrc[qoff + (size_t)(4*gq + i)*DD + 4*dq];
    }

    for (int g0 = 0; g0 < HPAD; g0 += 64) {
        __syncthreads();
#pragma unroll
        for (int i = 0; i < 4; ++i)
            *(bf16x4*)&As[(4*gq + i)*LSTR + 4*dq] = rA[i];
        {
            const bf16x4* rv = (MODE == 1) ? rV : rA;
#pragma unroll
            for (int j = 0; j < 4; ++j) {
                bf16x4 c = { rv[0][j], rv[1][j], rv[2][j], rv[3][j] };
                *(bf16x4*)&Vt[vaddr(4*dq + j, cgb)] = c;
            }
        }
        __syncthreads();

        if (g0 + 64 < HPAD) {
            const int gn = g0 + 64;
#pragma unroll
            for (int i = 0; i < 4; ++i) {
                rA[i] = *(const bf16x4*)&q2[qoff + (size_t)(gn + 4*gq + i)*DD + 4*dq];
                if (MODE == 1)
                    rV[i] = *(const bf16x4*)&vsrc[qoff + (size_t)(gn + 4*gq + i)*DD + 4*dq];
            }
        }

        const bool tail = (g0 + 64 > HP);

#pragma unroll
        for (int mt = 0; mt < 2; ++mt) {
            // ---- S-phase ----
            f32x16 C = {};
#pragma unroll
            for (int kt = 0; kt < 4; ++kt) {
                bf16x8 a = *(const bf16x8*)&As[(32*mt + lid)*LSTR + 16*kt + 8*half];
                C = __builtin_amdgcn_mfma_f32_32x32x16_bf16(a, bq1[kt], C, 0,0,0);
            }
            // ---- exp + pack PV A-frags ----
            bf16x8 af[2];
            float ls = 0.f;
#pragma unroll
            for (int s = 0; s < 16; ++s) {
                float e = EXP2(C[s] * SC);
                if (tail) {
                    const int gg = g0 + 32*mt + (s&3) + 8*(s>>2) + 4*half;
                    if (gg >= HP) e = 0.f;
                }
                ls += e;
                af[s>>3][s&7] = (bf16_t)e;
            }
            lacc += ls;
            // ---- PV ----
#pragma unroll
            for (int u = 0; u < 2; ++u) {
#pragma unroll
                for (int dt = 0; dt < 2; ++dt) {
                    const int chunk = (4*mt + 2*u + half) ^ vswz;
                    bf16x8 b = *(const bf16x8*)&Vt[(32*dt + lid)*64 + chunk*8];
                    O[dt] = __builtin_amdgcn_mfma_f32_32x32x16_bf16(af[u], b, O[dt], 0,0,0);
                }
            }
        }
    }

    // ---- epilogue ----
    const float l = lacc + __shfl_xor(lacc, 32);
    const float linv = 1.f / l;
#pragma unroll
    for (int s = 0; s < 16; ++s) {
        const int R = (s&3) + 8*(s>>2) + 4*half;
        const float li = __shfl(linv, R);
        const int hg = hb + R;
        if (hg < HP) {
#pragma unroll
            for (int dt = 0; dt < 2; ++dt) {
                const int d = 32*dt + lid;
                const float val = O[dt][s] * li;
                out[(((size_t)n*HP + hg)*FF + f)*DD + d] = fast_tanh(val);
                if (MODE == 0)
                    p1out[qoff + (size_t)hg*DD + d] = (bf16_t)val;
            }
        }
    }
}

extern "C" void kernel_launch(void* const* d_in, const int* in_sizes, int n_in,
                              void* d_out, int out_size, void* d_ws, size_t ws_size,
                              hipStream_t stream)
{
    const float* prot1 = (const float*)d_in[0];
    const float* prot2 = (const float*)d_in[1];
    const float* Wt    = (const float*)d_in[2];
    float* out = (float*)d_out;

    bf16_t* q1b = (bf16_t*)d_ws;
    bf16_t* q2b = q1b + QWS;
    bf16_t* p1b = q2b + QWS;
    float* Wp   = (float*)(p1b + QWS);

    wprep_kernel<<<dim3(448), 256, 0, stream>>>(Wt, Wp);
    conv_kernel<<<dim3(32, 4, 2), 256, 0, stream>>>(prot1, prot2, Wp, q1b, q2b);
    flash<0><<<dim3(8, NF), 256, 0, stream>>>(q1b, q2b, q2b, p1b, out);
    flash<1><<<dim3(8, NF), 256, 0, stream>>>(q1b, q2b, p1b, p1b, out + QOUT);
}

// Round 5
// 220.561 us; speedup vs baseline: 1.0881x; 1.0881x over previous
//
#include <hip/hip_runtime.h>
#include <math.h>

typedef __bf16 bf16_t;
typedef bf16_t bf16x4 __attribute__((ext_vector_type(4)));
typedef bf16_t bf16x8 __attribute__((ext_vector_type(8)));
typedef float  f32x16 __attribute__((ext_vector_type(16)));

#define HH 1024
#define CC 8
#define DD 64
#define FF 32
#define WW 7
#define HP 1018
#define HPAD 1024
#define NF 128
#define QOUT (NF*HP*DD)
#define QWS ((size_t)NF*HPAD*DD)

#if __has_builtin(__builtin_amdgcn_exp2f)
#define EXP2(x) __builtin_amdgcn_exp2f(x)
#else
#define EXP2(x) __expf((x) * 0.6931471805599453f)
#endif

// Vt: row stride 64 bf16, XOR-swizzled 8-element chunks (validated R4):
//   addr(row, col) = row*64 + (((col>>3) ^ (row&7) ^ ((row>>2)&7))<<3) + (col&7)
__device__ __forceinline__ int vaddr(int row, int col) {
    return row*64 + ((((col>>3) ^ (row&7) ^ ((row>>2)&7)))<<3) + (col&7);
}

// ---------------- W transpose: Wt[f][c][d][j] -> Wp[f][c][j][d] ----------------
__global__ __launch_bounds__(256) void wprep_kernel(
    const float* __restrict__ Wt, float* __restrict__ Wp)
{
    const int idx = blockIdx.x * 256 + threadIdx.x;
    if (idx < FF*CC*DD*WW) {
        const int j = idx % WW;
        int t = idx / WW;
        const int d = t % DD; t /= DD;
        const int c = t % CC;
        const int f = t / CC;
        Wp[((f*CC + c)*WW + j)*DD + d] = Wt[idx];
    }
}

// ---------------- projection (grouped conv): xs in [row][d][c] for b128 reads ----
__global__ __launch_bounds__(256) void conv_kernel(
    const float* __restrict__ x1, const float* __restrict__ x2,
    const float* __restrict__ Wp, bf16_t* __restrict__ q1, bf16_t* __restrict__ q2)
{
    __shared__ float xs[38*512];          // [row][d][c]: addr = row*512 + d*8 + c
    const float* x = blockIdx.z ? x2 : x1;
    bf16_t* q = blockIdx.z ? q2 : q1;
    const int n = blockIdx.y;
    const int hb = blockIdx.x * 32;
    const int tid = threadIdx.x;

    const float4* xg = (const float4*)(x + (size_t)n*HH*512);
    for (int i = tid; i < 38*128; i += 256) {
        const int row = hb + (i >> 7);
        float4 v = {0.f, 0.f, 0.f, 0.f};
        if (row < HH) v = xg[(size_t)row*128 + (i & 127)];
        const int r = i >> 7;
        const int c = (i & 127) >> 4;
        const int d0 = ((i & 127) & 15) * 4;
        xs[r*512 + (d0+0)*8 + c] = v.x;
        xs[r*512 + (d0+1)*8 + c] = v.y;
        xs[r*512 + (d0+2)*8 + c] = v.z;
        xs[r*512 + (d0+3)*8 + c] = v.w;
    }
    __syncthreads();

    const int d = tid & 63;
    const int fq = tid >> 6;
    for (int fi = 0; fi < 8; ++fi) {
        const int f = fq*8 + fi;
        float w[CC][WW];
#pragma unroll
        for (int c = 0; c < CC; ++c)
#pragma unroll
            for (int j = 0; j < WW; ++j)
                w[c][j] = Wp[((f*CC + c)*WW + j)*DD + d];
#pragma unroll
        for (int hc = 0; hc < 2; ++hc) {
            float acc[16];
#pragma unroll
            for (int i = 0; i < 16; ++i) acc[i] = 0.f;
#pragma unroll
            for (int rr = 0; rr < 22; ++rr) {
                const float4 a = *(const float4*)&xs[(hc*16 + rr)*512 + d*8 + 0];
                const float4 b = *(const float4*)&xs[(hc*16 + rr)*512 + d*8 + 4];
                const float xv[8] = {a.x, a.y, a.z, a.w, b.x, b.y, b.z, b.w};
#pragma unroll
                for (int j = 0; j < WW; ++j) {
                    const int i = rr - j;
                    if (i >= 0 && i < 16) {
#pragma unroll
                        for (int c = 0; c < CC; ++c)
                            acc[i] = fmaf(xv[c], w[c][j], acc[i]);
                    }
                }
            }
#pragma unroll
            for (int i = 0; i < 16; ++i) {
                const int h = hb + hc*16 + i;
                const float v = (h < HP) ? acc[i] : 0.f;
                q[((size_t)(n*FF + f)*HPAD + h)*DD + d] = (bf16_t)v;
            }
        }
    }
}

__device__ __forceinline__ float fast_tanh(float x) {
    const float t = __expf(2.f * x);
    return (t - 1.f) / (t + 1.f);
}

// ---------------- fused flash pass (MFMA), 64 h-rows/wave, A-frags from global ----
// Sᵀ = Q2·Q1ᵀ : C/D col=lane&31 -> h on lanes; row=(reg&3)+8*(reg>>2)+4*(lane>>5) -> g.
// A-frag (m=lane&31 row of q2-tile, 8 contiguous k) loaded DIRECTLY from global
// (L1/L2-hot, prefetched one tile ahead) -- no As LDS buffer at all.
template<int MODE>
__global__ __launch_bounds__(256, 2) void flash(
    const bf16_t* __restrict__ q1, const bf16_t* __restrict__ q2,
    const bf16_t* __restrict__ vsrc, bf16_t* __restrict__ p1out,
    float* __restrict__ out)
{
    __shared__ __align__(16) bf16_t Vt[64*64];     // V^T tile [d][p(g)], swizzled

    const int head = blockIdx.y;
    const int n = head >> 5, f = head & 31;
    const int tid = threadIdx.x;
    const int w = tid >> 6;
    const int lane = tid & 63;
    const int lid = lane & 31;
    const int half = lane >> 5;
    const int hb = blockIdx.x * 256 + w * 64;

    const size_t qoff = (size_t)head * HPAD * DD;
    const float SC = 1.442695041f / 1018.f;        // log2(e)/1018
    const int vswz = (lid & 7) ^ (lid >> 2);

    // Vt staging map: thread stages rows g=4gq..4gq+3, cols 4dq..4dq+3
    const int gq = tid >> 4;
    const int dq = tid & 15;
    const int cgb = 4*((gq>>1)&1) + 8*(gq&1) + 16*(gq>>2);   // permuted col base

    const bf16_t* vptr = (MODE == 1) ? vsrc : q2;

    // Q1 B-fragments, persistent in registers
    bf16x8 bq1[2][4];
#pragma unroll
    for (int nt = 0; nt < 2; ++nt)
#pragma unroll
        for (int kt = 0; kt < 4; ++kt)
            bq1[nt][kt] = *(const bf16x8*)&q1[qoff + (size_t)(hb + 32*nt + lid)*DD + 16*kt + 8*half];

    // A-fragments for tile 0 (from global)
    bf16x8 aq[2][4];
#pragma unroll
    for (int mt = 0; mt < 2; ++mt)
#pragma unroll
        for (int kt = 0; kt < 4; ++kt)
            aq[mt][kt] = *(const bf16x8*)&q2[qoff + (size_t)(32*mt + lid)*DD + 16*kt + 8*half];

    // V staging regs for tile 0
    bf16x4 rV[4];
#pragma unroll
    for (int i = 0; i < 4; ++i)
        rV[i] = *(const bf16x4*)&vptr[qoff + (size_t)(4*gq + i)*DD + 4*dq];

    f32x16 O[2][2] = {};
    float lacc[2] = {0.f, 0.f};

    for (int g0 = 0; g0 < HPAD; g0 += 64) {
        __syncthreads();                           // prev Vt fully consumed
#pragma unroll
        for (int j = 0; j < 4; ++j) {
            bf16x4 c = { rV[0][j], rV[1][j], rV[2][j], rV[3][j] };
            *(bf16x4*)&Vt[vaddr(4*dq + j, cgb)] = c;
        }
        __syncthreads();

        // prefetch next V tile (consumed next iteration)
        if (g0 + 64 < HPAD) {
#pragma unroll
            for (int i = 0; i < 4; ++i)
                rV[i] = *(const bf16x4*)&vptr[qoff + (size_t)(g0 + 64 + 4*gq + i)*DD + 4*dq];
        }

        const bool tail = (g0 + 64 > HP);

#pragma unroll
        for (int mt = 0; mt < 2; ++mt) {
            // ---- S-phase: A-frags from registers (global-prefetched) ----
            f32x16 C[2] = {};
#pragma unroll
            for (int kt = 0; kt < 4; ++kt) {
                C[0] = __builtin_amdgcn_mfma_f32_32x32x16_bf16(aq[mt][kt], bq1[0][kt], C[0], 0,0,0);
                C[1] = __builtin_amdgcn_mfma_f32_32x32x16_bf16(aq[mt][kt], bq1[1][kt], C[1], 0,0,0);
            }
            // reload this mt's A-frags for the NEXT tile (long latency window)
            if (g0 + 64 < HPAD) {
#pragma unroll
                for (int kt = 0; kt < 4; ++kt)
                    aq[mt][kt] = *(const bf16x8*)&q2[qoff + (size_t)(g0 + 64 + 32*mt + lid)*DD + 16*kt + 8*half];
            }
            // ---- exp + pack PV A-frags ----
            bf16x8 af[2][2];
#pragma unroll
            for (int nt = 0; nt < 2; ++nt) {
                float ls = 0.f;
#pragma unroll
                for (int s = 0; s < 16; ++s) {
                    float e = EXP2(C[nt][s] * SC);
                    if (tail) {
                        const int gg = g0 + 32*mt + (s&3) + 8*(s>>2) + 4*half;
                        if (gg >= HP) e = 0.f;
                    }
                    ls += e;
                    af[nt][s>>3][s&7] = (bf16_t)e;
                }
                lacc[nt] += ls;
            }
            // ---- PV: swizzled Vt b128 reads (conflict-free, validated R4) ----
#pragma unroll
            for (int u = 0; u < 2; ++u) {
#pragma unroll
                for (int dt = 0; dt < 2; ++dt) {
                    const int chunk = (4*mt + 2*u + half) ^ vswz;
                    bf16x8 b = *(const bf16x8*)&Vt[(32*dt + lid)*64 + chunk*8];
                    O[0][dt] = __builtin_amdgcn_mfma_f32_32x32x16_bf16(af[0][u], b, O[0][dt], 0,0,0);
                    O[1][dt] = __builtin_amdgcn_mfma_f32_32x32x16_bf16(af[1][u], b, O[1][dt], 0,0,0);
                }
            }
        }
    }

    // ---- epilogue ----
    float linv[2];
#pragma unroll
    for (int nt = 0; nt < 2; ++nt) {
        const float l = lacc[nt] + __shfl_xor(lacc[nt], 32);
        linv[nt] = 1.f / l;
    }
#pragma unroll
    for (int ht = 0; ht < 2; ++ht) {
#pragma unroll
        for (int s = 0; s < 16; ++s) {
            const int R = (s&3) + 8*(s>>2) + 4*half;
            const float li = __shfl(linv[ht], R);
            const int hg = hb + 32*ht + R;
#pragma unroll
            for (int dt = 0; dt < 2; ++dt) {
                const int d = 32*dt + lid;
                const float val = O[ht][dt][s] * li;
                if (hg < HP)
                    out[(((size_t)n*HP + hg)*FF + f)*DD + d] = fast_tanh(val);
                if (MODE == 0)   // zero-pad p1 rows >= HP so pass B stages clean data
                    p1out[qoff + (size_t)hg*DD + d] = (bf16_t)(hg < HP ? val : 0.f);
            }
        }
    }
}

extern "C" void kernel_launch(void* const* d_in, const int* in_sizes, int n_in,
                              void* d_out, int out_size, void* d_ws, size_t ws_size,
                              hipStream_t stream)
{
    const float* prot1 = (const float*)d_in[0];
    const float* prot2 = (const float*)d_in[1];
    const float* Wt    = (const float*)d_in[2];
    float* out = (float*)d_out;

    bf16_t* q1b = (bf16_t*)d_ws;
    bf16_t* q2b = q1b + QWS;
    bf16_t* p1b = q2b + QWS;
    float* Wp   = (float*)(p1b + QWS);

    wprep_kernel<<<dim3(448), 256, 0, stream>>>(Wt, Wp);
    conv_kernel<<<dim3(32, 4, 2), 256, 0, stream>>>(prot1, prot2, Wp, q1b, q2b);
    flash<0><<<dim3(4, NF), 256, 0, stream>>>(q1b, q2b, q2b, p1b, out);
    flash<1><<<dim3(4, NF), 256, 0, stream>>>(q1b, q2b, p1b, p1b, out + QOUT);
}